// Round 8
// baseline (61.609 us; speedup 1.0000x reference)
//
#include <hip/hip_runtime.h>

// RippleNetPlus fused — 1 block (256 thr) per batch element. DIM=32, HOP=2, MEM=32.
//
// Round 8: hoist phase A for BOTH hops before the hop loop.
// Rh[hop] = R(hop)@h(hop) depends only on indices+embeddings, not on GRU
// state M — so both hops' Rh compute runs up front as 8 independent
// unroll-1 iterations (2x load-pipeline depth), double-buffered into
// s_rh[2] (+4KB LDS -> 18.9KB, still 8 blocks/CU). Removes hop1's ~2400cy
// load chain from the serial path between GRU(hop0) and scores(hop1), and
// merges the init barrier into the post-A barrier (11 barriers vs 13).
// Phases B-E byte-identical to R7 (VGPR 64, no spill, dur 60.8).

#define NHOP 2

__device__ __forceinline__ float sigmoid_f(float x){ return 1.0f/(1.0f+__expf(-x)); }
__device__ __forceinline__ float tanh_f(float x){
  float e = __expf(2.0f*x);
  return 1.0f - 2.0f/(e + 1.0f);
}
__device__ __forceinline__ unsigned bf16_rtne(float x){
  unsigned u = __float_as_uint(x);
  return (u + 0x7fffu + ((u >> 16) & 1u)) >> 16;
}

__global__ __launch_bounds__(256) void ripple_fused(
    const int* __restrict__ h_i, const int* __restrict__ R_i, const int* __restrict__ t_i,
    const int* __restrict__ v_i,
    const float* __restrict__ entity_emb, const float* __restrict__ relation_emb,
    const float* __restrict__ agg_w1, const float* __restrict__ agg_b1,
    const float* __restrict__ agg_w2, const float* __restrict__ agg_b2,
    const float* __restrict__ gru_w_ih, const float* __restrict__ gru_w_hh,
    const float* __restrict__ gru_b_ih, const float* __restrict__ gru_b_hh,
    const float* __restrict__ ans_w, const float* __restrict__ ans_b,
    float* __restrict__ out)
{
  __shared__ __align__(16) uint2 s_wq[32*32];      // 8 KB bf16 quad, col o^i
  __shared__ __align__(16) float s_rh [2][8*32*4]; // 8 KB [hop][g][i]{m0..m3}
  __shared__ __align__(16) float s_vsM[32*2];      // [i]{vs,M}
  __shared__ __align__(16) float s_Z  [32];
  __shared__ __align__(16) float s_opart[8*32];    // 1 KB
  __shared__ __align__(16) float s_M  [32];
  __shared__ __align__(16) float s_gig[192];       // gi[0:96], gh[96:192]

  const int b   = blockIdx.x;
  const int tid = threadIdx.x;
  const int g   = tid >> 5;   // group 0..7
  const int o   = tid & 31;
  const int c   = o & 7;
  const int r_  = o >> 3;
  const bool bb4 = (c & 4) != 0;
  const bool bb2 = (c & 2) != 0;
  const bool bb1 = (c & 1) != 0;

  // ---- init: W quad, coalesced global reads -> bf16 RTNE -> swizzled LDS ----
  // (no barrier here: phase A doesn't read s_wq/s_vsM; the post-A barrier
  //  publishes these writes before phase B.)
  #pragma unroll
  for (int k = 0; k < 4; ++k){
    int ii = o;
    int oo = g + 8*k;
    float wa = agg_w1[oo*128       + ii];
    float wb = agg_w1[oo*128 + 32  + ii];
    float wc = agg_w1[oo*128 + 64  + ii];
    float wd = agg_w1[oo*128 + 96  + ii];
    s_wq[ii*32 + (oo ^ ii)] = make_uint2(bf16_rtne(wa) | (bf16_rtne(wb) << 16),
                                         bf16_rtne(wc) | (bf16_rtne(wd) << 16));
  }
  float Mreg = 0.f;
  if (tid < 32){
    float v = entity_emb[(size_t)v_i[b]*32 + o];
    s_vsM[o*2+0] = v; s_vsM[o*2+1] = v; s_M[o] = v;
    Mreg = v;
  }

  // ---- phase A (both hops): Rh for this group's 4 memories per hop ----
  // 8 independent unroll-1 iterations; rh result staged to s_rh[hp].
  {
    const int j = c*4 + r_;   // bijective lane->row for the staging write
    #pragma unroll 1
    for (int it = 0; it < 2*4; ++it){
      const int hp = it >> 2;
      const int ml = it & 3;
      const int ibase = (b*NHOP + hp)*32;
      int m    = g*4 + ml;
      int ridx = R_i[ibase + m];
      int hidx = h_i[ibase + m];
      const float* Rbase = relation_emb + (size_t)ridx*1024;
      float4 hv = *(const float4*)(entity_emb + (size_t)hidx*32 + c*4);
      float p[8];
      #pragma unroll
      for (int q = 0; q < 8; ++q){
        float4 rv = *(const float4*)(Rbase + q*128 + o*4);
        p[q] = rv.x*hv.x + rv.y*hv.y + rv.z*hv.z + rv.w*hv.w;
      }
      #pragma unroll
      for (int k = 0; k < 4; ++k){
        float send = bb4 ? p[k] : p[k+4];
        float t = __shfl_xor(send, 4);
        p[k] = (bb4 ? p[k+4] : p[k]) + t;
      }
      #pragma unroll
      for (int k = 0; k < 2; ++k){
        float send = bb2 ? p[k] : p[k+2];
        float t = __shfl_xor(send, 2);
        p[k] = (bb2 ? p[k+2] : p[k]) + t;
      }
      {
        float send = bb1 ? p[0] : p[1];
        float t = __shfl_xor(send, 1);
        p[0] = (bb1 ? p[1] : p[0]) + t;
      }
      // lane j's row, element ml of the float4 slot
      s_rh[hp][(g*32 + j)*4 + ml] = p[0];
    }
  }
  __syncthreads();

  const float b1v = agg_b1[o];
  const float w2v = agg_w2[o];

  for (int hop = 0; hop < NHOP; ++hop){
    const int ibase = (b*NHOP + hop)*32;
    const float* bufC = s_rh[hop];

    // ---- t-row prefetch (latency hides under phase B) ----
    float tv[4];
    #pragma unroll
    for (int ml = 0; ml < 4; ++ml)
      tv[ml] = entity_emb[(size_t)t_i[ibase + g*4 + ml]*32 + o];

    // ---- phase B: hidden + score, 4 memories per group ----
    {
      const float4* rh_p = (const float4*)&bufC[(g*32)*4];
      float a0=0.f, a1=0.f, a2=0.f, a3=0.f;
      #pragma unroll 4
      for (int i = 0; i < 32; ++i){
        uint2 wd2 = s_wq[i*32 + (o ^ i)];
        float wa = __uint_as_float(wd2.x << 16);
        float wb = __uint_as_float(wd2.x & 0xffff0000u);
        float wc = __uint_as_float(wd2.y << 16);
        float wd = __uint_as_float(wd2.y & 0xffff0000u);
        float2 vm = *(const float2*)&s_vsM[i*2];
        float  cp = vm.x*wa + vm.y*wb;
        float4 rh = rh_p[i];
        a0 += rh.x*cp + fabsf(rh.x-vm.x)*wc + fabsf(rh.x-vm.y)*wd;
        a1 += rh.y*cp + fabsf(rh.y-vm.x)*wc + fabsf(rh.y-vm.y)*wd;
        a2 += rh.z*cp + fabsf(rh.z-vm.x)*wc + fabsf(rh.z-vm.y)*wd;
        a3 += rh.w*cp + fabsf(rh.w-vm.x)*wc + fabsf(rh.w-vm.y)*wd;
      }
      float v4[4];
      v4[0] = tanh_f(a0 + b1v) * w2v;
      v4[1] = tanh_f(a1 + b1v) * w2v;
      v4[2] = tanh_f(a2 + b1v) * w2v;
      v4[3] = tanh_f(a3 + b1v) * w2v;
      // packed butterfly: 4 values over 32 lanes (6 shfl)
      const bool t4 = (o & 16) != 0;
      #pragma unroll
      for (int k = 0; k < 2; ++k){
        float send = t4 ? v4[k] : v4[k+2];
        float t = __shfl_xor(send, 16);
        v4[k] = (t4 ? v4[k+2] : v4[k]) + t;
      }
      const bool t3 = (o & 8) != 0;
      {
        float send = t3 ? v4[0] : v4[1];
        float t = __shfl_xor(send, 8);
        v4[0] = (t3 ? v4[1] : v4[0]) + t;
      }
      v4[0] += __shfl_xor(v4[0], 4);
      v4[0] += __shfl_xor(v4[0], 2);
      v4[0] += __shfl_xor(v4[0], 1);
      if ((o & 7) == 0){
        int ml = ((o >> 4) & 1)*2 + ((o >> 3) & 1);
        s_Z[g*4 + ml] = v4[0];
      }
    }
    __syncthreads();

    // ---- phase C: softmax on all lanes; weighted-t partials ----
    {
      float z  = s_Z[o];
      float mx = z;
      #pragma unroll
      for (int s = 16; s > 0; s >>= 1) mx = fmaxf(mx, __shfl_xor(mx, s));
      float e  = __expf(z - mx);
      float sm = e;
      #pragma unroll
      for (int s = 16; s > 0; s >>= 1) sm += __shfl_xor(sm, s);
      float gval = e / sm;   // lane o holds gate for memory o
      float po = 0.f;
      #pragma unroll
      for (int ml = 0; ml < 4; ++ml)
        po += __shfl(gval, g*4 + ml) * tv[ml];
      s_opart[g*32 + o] = po;
    }
    __syncthreads();

    // ---- phase D: GRU gates, distributed, coalesced b128 weight loads ----
    {
      const int cc = (tid & 7) * 4;
      const int rr = tid >> 3;          // 0..31
      float4 o4 = make_float4(0,0,0,0);
      #pragma unroll
      for (int gg = 0; gg < 8; ++gg){
        float4 t = *(const float4*)&s_opart[gg*32 + cc];
        o4.x += t.x; o4.y += t.y; o4.z += t.z; o4.w += t.w;
      }
      float4 m4 = *(const float4*)&s_M[cc];
      #pragma unroll
      for (int k = 0; k < 3; ++k){
        int row = k*32 + rr;
        float4 wi = *(const float4*)(gru_w_ih + ((size_t)hop*96 + row)*32 + cc);
        float4 wh = *(const float4*)(gru_w_hh + ((size_t)hop*96 + row)*32 + cc);
        float ai = wi.x*o4.x + wi.y*o4.y + wi.z*o4.z + wi.w*o4.w;
        float ah = wh.x*m4.x + wh.y*m4.y + wh.z*m4.z + wh.w*m4.w;
        ai += __shfl_xor(ai,1); ai += __shfl_xor(ai,2); ai += __shfl_xor(ai,4);
        ah += __shfl_xor(ah,1); ah += __shfl_xor(ah,2); ah += __shfl_xor(ah,4);
        if ((tid & 7) == 0){
          s_gig[row]      = ai;
          s_gig[96 + row] = ah;
        }
      }
    }
    __syncthreads();

    // ---- phase E: GRU state update (lanes 0..31), biases from global ----
    if (tid < 32){
      const float* bih = gru_b_ih + hop*96;
      const float* bhh = gru_b_hh + hop*96;
      float ir = s_gig[o]       + bih[o];
      float iz = s_gig[32 + o]  + bih[32 + o];
      float in_= s_gig[64 + o]  + bih[64 + o];
      float hr = s_gig[96 + o]  + bhh[o];
      float hz = s_gig[128 + o] + bhh[32 + o];
      float hn = s_gig[160 + o] + bhh[64 + o];
      float r  = sigmoid_f(ir + hr);
      float zz = sigmoid_f(iz + hz);
      float n  = tanh_f(in_ + r*hn);
      float Mn = (1.f - zz)*n + zz*Mreg;
      Mreg = Mn;
      s_M[o] = Mn;
      s_vsM[o*2+1] = Mn;
    }
    __syncthreads();
  }

  // ---- epilogue: Mw = sigmoid(M @ ans_w.T + ans_b); out = vs . Mw ----
  {
    const int cc = (tid & 7) * 4;
    const int rr = tid >> 3;
    float4 m4 = *(const float4*)&s_M[cc];
    float4 aw = *(const float4*)(ans_w + (size_t)rr*32 + cc);
    float a = aw.x*m4.x + aw.y*m4.y + aw.z*m4.z + aw.w*m4.w;
    a += __shfl_xor(a,1); a += __shfl_xor(a,2); a += __shfl_xor(a,4);
    if ((tid & 7) == 0) s_Z[rr] = sigmoid_f(a + ans_b[rr]);
  }
  __syncthreads();
  if (tid < 32){
    float val = s_vsM[o*2+0] * s_Z[o];
    #pragma unroll
    for (int s = 16; s > 0; s >>= 1) val += __shfl_xor(val, s);
    if (tid == 0) out[b] = val;
  }
}

extern "C" void kernel_launch(void* const* d_in, const int* in_sizes, int n_in,
                              void* d_out, int out_size, void* d_ws, size_t ws_size,
                              hipStream_t stream) {
  const int*   h_i          = (const int*)  d_in[0];
  const int*   R_i          = (const int*)  d_in[1];
  const int*   t_i          = (const int*)  d_in[2];
  const int*   v_i          = (const int*)  d_in[3];
  const float* entity_emb   = (const float*)d_in[4];
  const float* relation_emb = (const float*)d_in[5];
  const float* agg_w1       = (const float*)d_in[6];
  const float* agg_b1       = (const float*)d_in[7];
  const float* agg_w2       = (const float*)d_in[8];
  const float* agg_b2       = (const float*)d_in[9];   // softmax-invariant, dropped
  const float* gru_w_ih     = (const float*)d_in[10];
  const float* gru_w_hh     = (const float*)d_in[11];
  const float* gru_b_ih     = (const float*)d_in[12];
  const float* gru_b_hh     = (const float*)d_in[13];
  const float* ans_w        = (const float*)d_in[14];
  const float* ans_b        = (const float*)d_in[15];
  (void)agg_b2;
  float* outp = (float*)d_out;

  const int batch = in_sizes[3];
  ripple_fused<<<batch, 256, 0, stream>>>(
      h_i, R_i, t_i, v_i, entity_emb, relation_emb,
      agg_w1, agg_b1, agg_w2, agg_b2,
      gru_w_ih, gru_w_hh, gru_b_ih, gru_b_hh,
      ans_w, ans_b, outp);
}

// Round 9
// 55.014 us; speedup vs baseline: 1.1199x; 1.1199x over previous
//
#include <hip/hip_runtime.h>
#include <hip/hip_bf16.h>

// RippleNetPlus fused — 1 block (256 thr) per batch element. DIM=32, HOP=2, MEM=32.
//
// Round 9: phase B on matrix cores. The score-MLP hidden layer is
//   hidden[m][o] = Sum_x A_x[m][i] B_x[i][o],  x in {Rh*vs, Rh*M, |Rh-vs|, |Rh-M|}
// i.e. four 32x32x32 matmuls -> 8x v_mfma_f32_32x32x16_bf16 per hop,
// replacing the ~870-VALU/thread i-loop with ~350 inst/thread.
//  - B-frags (hop-invariant W1 column blocks) staged bf16 in LDS at init.
//  - phase A writes Rh directly in per-lane A-source order (stride-18 rows,
//    conflict-free b64 reads in B).
//  - D layout (verified m74/m101): col=lane&31, row=(reg&3)+8*(reg>>2)+4*(lane>>5).
//    Epilogue: 16x tanh*w2 + packed butterfly over o -> Z[m], wave 0 writes.
//  - phases A/C/D/E unchanged from R8 (VGPR 64, no spill at 60.8us).

#define NHOP 2

typedef __attribute__((ext_vector_type(16))) float f32x16;
typedef __attribute__((ext_vector_type(8)))  short bf16x8s;
typedef __attribute__((ext_vector_type(4)))  int   i32x4;

__device__ __forceinline__ float sigmoid_f(float x){ return 1.0f/(1.0f+__expf(-x)); }
__device__ __forceinline__ float tanh_f(float x){
  float e = __expf(2.0f*x);
  return 1.0f - 2.0f/(e + 1.0f);
}
__device__ __forceinline__ unsigned pk_bf16(float lo, float hi){
  __hip_bfloat162 h = __float22bfloat162_rn(make_float2(lo, hi));
  return *reinterpret_cast<unsigned*>(&h);
}

__global__ __launch_bounds__(256) void ripple_fused(
    const int* __restrict__ h_i, const int* __restrict__ R_i, const int* __restrict__ t_i,
    const int* __restrict__ v_i,
    const float* __restrict__ entity_emb, const float* __restrict__ relation_emb,
    const float* __restrict__ agg_w1, const float* __restrict__ agg_b1,
    const float* __restrict__ agg_w2, const float* __restrict__ agg_b2,
    const float* __restrict__ gru_w_ih, const float* __restrict__ gru_w_hh,
    const float* __restrict__ gru_b_ih, const float* __restrict__ gru_b_hh,
    const float* __restrict__ ans_w, const float* __restrict__ ans_b,
    float* __restrict__ out)
{
  __shared__ __align__(16) int   s_bfrag[512*4];    // 8 KB  B-frags [x*2+t][lane] int4
  __shared__ __align__(16) float s_rhA[2][64*18];   // 9 KB  Rh in A-source order
  __shared__ __align__(16) float s_vsM[32*2];       // [i]{vs,M}
  __shared__ __align__(16) float s_Z  [32];
  __shared__ __align__(16) float s_opart[8*32];     // 1 KB
  __shared__ __align__(16) float s_M  [32];
  __shared__ __align__(16) float s_gig[192];        // gi[0:96], gh[96:192]

  const int b   = blockIdx.x;
  const int tid = threadIdx.x;
  const int g   = tid >> 5;   // group 0..7
  const int o   = tid & 31;
  const int l   = tid & 63;   // lane
  const int c   = o & 7;
  const int r_  = o >> 3;
  const bool bb4 = (c & 4) != 0;
  const bool bb2 = (c & 2) != 0;
  const bool bb1 = (c & 1) != 0;

  // ---- init: stage B-fragments. B_x[i][o2] = agg_w1[o2*128 + 32x + i];
  //      lane li of frag (x,t) holds elems i = 16t + 8*(li>>5) + j, o2 = li&31.
  #pragma unroll
  for (int k = 0; k < 2; ++k){
    int s  = tid + k*256;
    int xt = s >> 6, li = s & 63;
    int x  = xt >> 1, t = xt & 1;
    const float* src = agg_w1 + (li & 31)*128 + x*32 + t*16 + ((li >> 5) & 1)*8;
    float4 f0 = *(const float4*)src;
    float4 f1 = *(const float4*)(src + 4);
    *(int4*)&s_bfrag[s*4] = make_int4((int)pk_bf16(f0.x, f0.y), (int)pk_bf16(f0.z, f0.w),
                                      (int)pk_bf16(f1.x, f1.y), (int)pk_bf16(f1.z, f1.w));
  }
  float Mreg = 0.f;
  if (tid < 32){
    float v = entity_emb[(size_t)v_i[b]*32 + o];
    s_vsM[o*2+0] = v; s_vsM[o*2+1] = v; s_M[o] = v;
    Mreg = v;
  }

  // ---- phase A (both hops): Rh, coalesced loads + butterfly; write s_rhA in
  //      A-source order: value (i,m) -> float ( (((i>>3)&1)*32 + m)*18 + (i>>4)*8 + (i&7) )
  {
    const int iA  = c*4 + r_;                 // this lane's Rh row index i
    const int pos = ((iA >> 4) & 1)*8 + (iA & 7);
    const int hA  = (iA >> 3) & 1;
    #pragma unroll 1
    for (int it = 0; it < 2*4; ++it){
      const int hp = it >> 2;
      const int ml = it & 3;
      const int ibase = (b*NHOP + hp)*32;
      int m    = g*4 + ml;
      int ridx = R_i[ibase + m];
      int hidx = h_i[ibase + m];
      const float* Rbase = relation_emb + (size_t)ridx*1024;
      float4 hv = *(const float4*)(entity_emb + (size_t)hidx*32 + c*4);
      float p[8];
      #pragma unroll
      for (int q = 0; q < 8; ++q){
        float4 rv = *(const float4*)(Rbase + q*128 + o*4);
        p[q] = rv.x*hv.x + rv.y*hv.y + rv.z*hv.z + rv.w*hv.w;
      }
      #pragma unroll
      for (int k = 0; k < 4; ++k){
        float send = bb4 ? p[k] : p[k+4];
        float t = __shfl_xor(send, 4);
        p[k] = (bb4 ? p[k+4] : p[k]) + t;
      }
      #pragma unroll
      for (int k = 0; k < 2; ++k){
        float send = bb2 ? p[k] : p[k+2];
        float t = __shfl_xor(send, 2);
        p[k] = (bb2 ? p[k+2] : p[k]) + t;
      }
      {
        float send = bb1 ? p[0] : p[1];
        float t = __shfl_xor(send, 1);
        p[0] = (bb1 ? p[1] : p[0]) + t;
      }
      s_rhA[hp][(hA*32 + m)*18 + pos] = p[0];
    }
  }
  __syncthreads();

  const float b1v = agg_b1[o];
  const float w2v = agg_w2[o];

  for (int hop = 0; hop < NHOP; ++hop){
    const int ibase = (b*NHOP + hop)*32;

    // ---- t-row prefetch (latency hides under phase B) ----
    float tv[4];
    #pragma unroll
    for (int ml = 0; ml < 4; ++ml)
      tv[ml] = entity_emb[(size_t)t_i[ibase + g*4 + ml]*32 + o];

    // ---- phase B: 8x MFMA, all waves redundant; wave 0 publishes Z ----
    {
      f32x16 acc;
      #pragma unroll
      for (int r = 0; r < 16; ++r) acc[r] = 0.f;

      #pragma unroll 1
      for (int t = 0; t < 2; ++t){
        const float* rp = &s_rhA[hop][l*18 + t*8];
        float2 q0 = *(const float2*)(rp + 0);
        float2 q1 = *(const float2*)(rp + 2);
        float2 q2 = *(const float2*)(rp + 4);
        float2 q3 = *(const float2*)(rp + 6);
        float rh[8] = {q0.x,q0.y,q1.x,q1.y,q2.x,q2.y,q3.x,q3.y};
        const int ib = t*16 + ((l >> 5) & 1)*8;
        unsigned aw[4][4];
        #pragma unroll
        for (int q = 0; q < 4; ++q){
          float2 vm0 = *(const float2*)&s_vsM[(ib + 2*q)*2];
          float2 vm1 = *(const float2*)&s_vsM[(ib + 2*q + 1)*2];
          float e0 = rh[2*q], e1 = rh[2*q+1];
          aw[0][q] = pk_bf16(e0*vm0.x,        e1*vm1.x);
          aw[1][q] = pk_bf16(e0*vm0.y,        e1*vm1.y);
          aw[2][q] = pk_bf16(fabsf(e0-vm0.x), fabsf(e1-vm1.x));
          aw[3][q] = pk_bf16(fabsf(e0-vm0.y), fabsf(e1-vm1.y));
        }
        #pragma unroll
        for (int x = 0; x < 4; ++x){
          i32x4 av = {(int)aw[x][0], (int)aw[x][1], (int)aw[x][2], (int)aw[x][3]};
          i32x4 bv = *(const i32x4*)&s_bfrag[((x*2 + t)*64 + l)*4];
          acc = __builtin_amdgcn_mfma_f32_32x32x16_bf16(
                  __builtin_bit_cast(bf16x8s, av),
                  __builtin_bit_cast(bf16x8s, bv), acc, 0, 0, 0);
        }
      }

      // epilogue: Z[m] = sum_o tanh(D[m][o]+b1[o])*w2[o]; packed butterfly over o
      float v[16];
      #pragma unroll
      for (int r = 0; r < 16; ++r) v[r] = tanh_f(acc[r] + b1v) * w2v;
      const bool qb0 = (l & 1) != 0;
      #pragma unroll
      for (int k = 0; k < 8; ++k){
        float send = qb0 ? v[k] : v[k+8];
        float tt = __shfl_xor(send, 1);
        v[k] = (qb0 ? v[k+8] : v[k]) + tt;
      }
      const bool qb1 = (l & 2) != 0;
      #pragma unroll
      for (int k = 0; k < 4; ++k){
        float send = qb1 ? v[k] : v[k+4];
        float tt = __shfl_xor(send, 2);
        v[k] = (qb1 ? v[k+4] : v[k]) + tt;
      }
      const bool qb2 = (l & 4) != 0;
      #pragma unroll
      for (int k = 0; k < 2; ++k){
        float send = qb2 ? v[k] : v[k+2];
        float tt = __shfl_xor(send, 4);
        v[k] = (qb2 ? v[k+2] : v[k]) + tt;
      }
      const bool qb3 = (l & 8) != 0;
      {
        float send = qb3 ? v[0] : v[1];
        float tt = __shfl_xor(send, 8);
        v[0] = (qb3 ? v[1] : v[0]) + tt;
      }
      v[0] += __shfl_xor(v[0], 16);
      if (tid < 64 && !(l & 16)){
        int m = ((l & 1) << 4) | (((l >> 1) & 1) << 3) | (((l >> 5) & 1) << 2)
              | (((l >> 2) & 1) << 1) | ((l >> 3) & 1);
        s_Z[m] = v[0];
      }
    }
    __syncthreads();

    // ---- phase C: softmax on all lanes; weighted-t partials ----
    {
      float z  = s_Z[o];
      float mx = z;
      #pragma unroll
      for (int s = 16; s > 0; s >>= 1) mx = fmaxf(mx, __shfl_xor(mx, s));
      float e  = __expf(z - mx);
      float sm = e;
      #pragma unroll
      for (int s = 16; s > 0; s >>= 1) sm += __shfl_xor(sm, s);
      float gval = e / sm;   // lane o holds gate for memory o
      float po = 0.f;
      #pragma unroll
      for (int ml = 0; ml < 4; ++ml)
        po += __shfl(gval, g*4 + ml) * tv[ml];
      s_opart[g*32 + o] = po;
    }
    __syncthreads();

    // ---- phase D: GRU gates, distributed, coalesced b128 weight loads ----
    {
      const int cc = (tid & 7) * 4;
      const int rr = tid >> 3;          // 0..31
      float4 o4 = make_float4(0,0,0,0);
      #pragma unroll
      for (int gg = 0; gg < 8; ++gg){
        float4 t = *(const float4*)&s_opart[gg*32 + cc];
        o4.x += t.x; o4.y += t.y; o4.z += t.z; o4.w += t.w;
      }
      float4 m4 = *(const float4*)&s_M[cc];
      #pragma unroll
      for (int k = 0; k < 3; ++k){
        int row = k*32 + rr;
        float4 wi = *(const float4*)(gru_w_ih + ((size_t)hop*96 + row)*32 + cc);
        float4 wh = *(const float4*)(gru_w_hh + ((size_t)hop*96 + row)*32 + cc);
        float ai = wi.x*o4.x + wi.y*o4.y + wi.z*o4.z + wi.w*o4.w;
        float ah = wh.x*m4.x + wh.y*m4.y + wh.z*m4.z + wh.w*m4.w;
        ai += __shfl_xor(ai,1); ai += __shfl_xor(ai,2); ai += __shfl_xor(ai,4);
        ah += __shfl_xor(ah,1); ah += __shfl_xor(ah,2); ah += __shfl_xor(ah,4);
        if ((tid & 7) == 0){
          s_gig[row]      = ai;
          s_gig[96 + row] = ah;
        }
      }
    }
    __syncthreads();

    // ---- phase E: GRU state update (lanes 0..31), biases from global ----
    if (tid < 32){
      const float* bih = gru_b_ih + hop*96;
      const float* bhh = gru_b_hh + hop*96;
      float ir = s_gig[o]       + bih[o];
      float iz = s_gig[32 + o]  + bih[32 + o];
      float in_= s_gig[64 + o]  + bih[64 + o];
      float hr = s_gig[96 + o]  + bhh[o];
      float hz = s_gig[128 + o] + bhh[32 + o];
      float hn = s_gig[160 + o] + bhh[64 + o];
      float r  = sigmoid_f(ir + hr);
      float zz = sigmoid_f(iz + hz);
      float n  = tanh_f(in_ + r*hn);
      float Mn = (1.f - zz)*n + zz*Mreg;
      Mreg = Mn;
      s_M[o] = Mn;
      s_vsM[o*2+1] = Mn;
    }
    __syncthreads();
  }

  // ---- epilogue: Mw = sigmoid(M @ ans_w.T + ans_b); out = vs . Mw ----
  {
    const int cc = (tid & 7) * 4;
    const int rr = tid >> 3;
    float4 m4 = *(const float4*)&s_M[cc];
    float4 aw = *(const float4*)(ans_w + (size_t)rr*32 + cc);
    float a = aw.x*m4.x + aw.y*m4.y + aw.z*m4.z + aw.w*m4.w;
    a += __shfl_xor(a,1); a += __shfl_xor(a,2); a += __shfl_xor(a,4);
    if ((tid & 7) == 0) s_Z[rr] = sigmoid_f(a + ans_b[rr]);
  }
  __syncthreads();
  if (tid < 32){
    float val = s_vsM[o*2+0] * s_Z[o];
    #pragma unroll
    for (int s = 16; s > 0; s >>= 1) val += __shfl_xor(val, s);
    if (tid == 0) out[b] = val;
  }
}

extern "C" void kernel_launch(void* const* d_in, const int* in_sizes, int n_in,
                              void* d_out, int out_size, void* d_ws, size_t ws_size,
                              hipStream_t stream) {
  const int*   h_i          = (const int*)  d_in[0];
  const int*   R_i          = (const int*)  d_in[1];
  const int*   t_i          = (const int*)  d_in[2];
  const int*   v_i          = (const int*)  d_in[3];
  const float* entity_emb   = (const float*)d_in[4];
  const float* relation_emb = (const float*)d_in[5];
  const float* agg_w1       = (const float*)d_in[6];
  const float* agg_b1       = (const float*)d_in[7];
  const float* agg_w2       = (const float*)d_in[8];
  const float* agg_b2       = (const float*)d_in[9];   // softmax-invariant, dropped
  const float* gru_w_ih     = (const float*)d_in[10];
  const float* gru_w_hh     = (const float*)d_in[11];
  const float* gru_b_ih     = (const float*)d_in[12];
  const float* gru_b_hh     = (const float*)d_in[13];
  const float* ans_w        = (const float*)d_in[14];
  const float* ans_b        = (const float*)d_in[15];
  (void)agg_b2;
  float* outp = (float*)d_out;

  const int batch = in_sizes[3];
  ripple_fused<<<batch, 256, 0, stream>>>(
      h_i, R_i, t_i, v_i, entity_emb, relation_emb,
      agg_w1, agg_b1, agg_w2, agg_b2,
      gru_w_ih, gru_w_hh, gru_b_ih, gru_b_hh,
      ans_w, ans_b, outp);
}

// Round 10
// 45.279 us; speedup vs baseline: 1.3607x; 1.2150x over previous
//
#include <hip/hip_runtime.h>
#include <hip/hip_bf16.h>

// RippleNetPlus fused — 1 block (256 thr) per batch element. DIM=32, HOP=2, MEM=32.
//
// Round 10: phase B de-duplicated. Hidden(32m x 32o) = four 16x16 tiles;
// wave w owns tile (mt=w>>1, ot=w&1) via mfma_f32_16x16x32_bf16 (K=32 in one
// instruction, 4 MFMA per wave for the 4 x-terms) instead of all 4 waves
// redundantly doing 8x 32x32x16. A-prep halves, tanh 16->4, o-reduce 31->5
// shfl. Partial Z per ot-half -> s_zpart; combine folded into phase C read
// (no extra barrier). Phase A writes Rh [m][i] stride-33 (odd stride,
// conflict-free; feeds A-frag b128 reads). C/D: col=lane&15,
// row=(lane>>4)*4+reg (m89-verified). Phases A/C/D/E else unchanged from R9
// (55.0us, VGPR 52, no spill).

#define NHOP 2

typedef __attribute__((ext_vector_type(4)))  float f32x4;
typedef __attribute__((ext_vector_type(8)))  short bf16x8s;
typedef __attribute__((ext_vector_type(4)))  int   i32x4;

__device__ __forceinline__ float sigmoid_f(float x){ return 1.0f/(1.0f+__expf(-x)); }
__device__ __forceinline__ float tanh_f(float x){
  float e = __expf(2.0f*x);
  return 1.0f - 2.0f/(e + 1.0f);
}
__device__ __forceinline__ unsigned pk_bf16(float lo, float hi){
  __hip_bfloat162 h = __float22bfloat162_rn(make_float2(lo, hi));
  return *reinterpret_cast<unsigned*>(&h);
}

__global__ __launch_bounds__(256) void ripple_fused(
    const int* __restrict__ h_i, const int* __restrict__ R_i, const int* __restrict__ t_i,
    const int* __restrict__ v_i,
    const float* __restrict__ entity_emb, const float* __restrict__ relation_emb,
    const float* __restrict__ agg_w1, const float* __restrict__ agg_b1,
    const float* __restrict__ agg_w2, const float* __restrict__ agg_b2,
    const float* __restrict__ gru_w_ih, const float* __restrict__ gru_w_hh,
    const float* __restrict__ gru_b_ih, const float* __restrict__ gru_b_hh,
    const float* __restrict__ ans_w, const float* __restrict__ ans_b,
    float* __restrict__ out)
{
  __shared__ __align__(16) int   s_bfrag[8*64*4];   // 8 KB  B-frags [x*2+ot][lane] int4
  __shared__ __align__(16) float s_rhA[2][32*33];   // 8.25KB Rh rows stride 33
  __shared__ __align__(16) float s_vsM[32*2];       // [i]{vs,M}
  __shared__ __align__(16) float s_zpart[64];       // [ot][m] partial Z
  __shared__ __align__(16) float s_opart[8*32];     // 1 KB
  __shared__ __align__(16) float s_M  [32];
  __shared__ __align__(16) float s_gig[192];        // gi[0:96], gh[96:192]

  const int b   = blockIdx.x;
  const int tid = threadIdx.x;
  const int g   = tid >> 5;   // group 0..7 (phase A/C granularity)
  const int o   = tid & 31;
  const int l   = tid & 63;   // lane
  const int w   = tid >> 6;   // wave 0..3
  const int c   = o & 7;
  const int r_  = o >> 3;
  const bool bb4 = (c & 4) != 0;
  const bool bb2 = (c & 2) != 0;
  const bool bb1 = (c & 1) != 0;

  // ---- init: stage B-fragments for 16x16x32. Frag f = x*2+ot; lane li holds
  //      B_x[i][o2], o2 = ot*16 + (li&15), i = (li>>4)*8 + j (j=0..7).
  #pragma unroll
  for (int k = 0; k < 2; ++k){
    int s  = tid + k*256;           // 0..511
    int f  = s >> 6, li = s & 63;
    int x  = f >> 1, ot = f & 1;
    const float* src = agg_w1 + (ot*16 + (li & 15))*128 + x*32 + ((li >> 4) & 3)*8;
    float4 f0 = *(const float4*)src;
    float4 f1 = *(const float4*)(src + 4);
    *(int4*)&s_bfrag[s*4] = make_int4((int)pk_bf16(f0.x, f0.y), (int)pk_bf16(f0.z, f0.w),
                                      (int)pk_bf16(f1.x, f1.y), (int)pk_bf16(f1.z, f1.w));
  }
  float Mreg = 0.f;
  if (tid < 32){
    float v = entity_emb[(size_t)v_i[b]*32 + o];
    s_vsM[o*2+0] = v; s_vsM[o*2+1] = v; s_M[o] = v;
    Mreg = v;
  }

  // ---- phase A (both hops): Rh, coalesced loads + butterfly ->
  //      s_rhA[hp][m*33 + i]  (i = c*4+r_ distinct per lane in group: no conflict)
  {
    const int iA = c*4 + r_;
    #pragma unroll 1
    for (int it = 0; it < 2*4; ++it){
      const int hp = it >> 2;
      const int ml = it & 3;
      const int ibase = (b*NHOP + hp)*32;
      int m    = g*4 + ml;
      int ridx = R_i[ibase + m];
      int hidx = h_i[ibase + m];
      const float* Rbase = relation_emb + (size_t)ridx*1024;
      float4 hv = *(const float4*)(entity_emb + (size_t)hidx*32 + c*4);
      float p[8];
      #pragma unroll
      for (int q = 0; q < 8; ++q){
        float4 rv = *(const float4*)(Rbase + q*128 + o*4);
        p[q] = rv.x*hv.x + rv.y*hv.y + rv.z*hv.z + rv.w*hv.w;
      }
      #pragma unroll
      for (int k = 0; k < 4; ++k){
        float send = bb4 ? p[k] : p[k+4];
        float t = __shfl_xor(send, 4);
        p[k] = (bb4 ? p[k+4] : p[k]) + t;
      }
      #pragma unroll
      for (int k = 0; k < 2; ++k){
        float send = bb2 ? p[k] : p[k+2];
        float t = __shfl_xor(send, 2);
        p[k] = (bb2 ? p[k+2] : p[k]) + t;
      }
      {
        float send = bb1 ? p[0] : p[1];
        float t = __shfl_xor(send, 1);
        p[0] = (bb1 ? p[1] : p[0]) + t;
      }
      s_rhA[hp][m*33 + iA] = p[0];
    }
  }
  __syncthreads();

  // per-wave tile coords + per-lane tanh constants (col o2 = ot*16 + (l&15))
  const int mt  = w >> 1, ot = w & 1;
  const int col = l & 15;
  const int kg  = l >> 4;          // k-octet 0..3
  const float b1o = agg_b1[ot*16 + col];
  const float w2o = agg_w2[ot*16 + col];

  for (int hop = 0; hop < NHOP; ++hop){
    const int ibase = (b*NHOP + hop)*32;

    // ---- t-row prefetch (latency hides under phase B) ----
    float tv[4];
    #pragma unroll
    for (int ml = 0; ml < 4; ++ml)
      tv[ml] = entity_emb[(size_t)t_i[ibase + g*4 + ml]*32 + o];

    // ---- phase B: wave-private 16x16 tile, 4x mfma_f32_16x16x32_bf16 ----
    {
      const int m = mt*16 + col;                      // A row (memory index)
      const float* rp = &s_rhA[hop][m*33 + kg*8];
      float4 q0 = *(const float4*)(rp);
      float4 q1 = *(const float4*)(rp + 4);
      float rh[8] = {q0.x,q0.y,q0.z,q0.w,q1.x,q1.y,q1.z,q1.w};
      unsigned aw[4][4];
      #pragma unroll
      for (int q = 0; q < 4; ++q){
        int i0 = kg*8 + 2*q;
        float2 vm0 = *(const float2*)&s_vsM[i0*2];
        float2 vm1 = *(const float2*)&s_vsM[(i0+1)*2];
        float e0 = rh[2*q], e1 = rh[2*q+1];
        aw[0][q] = pk_bf16(e0*vm0.x,        e1*vm1.x);
        aw[1][q] = pk_bf16(e0*vm0.y,        e1*vm1.y);
        aw[2][q] = pk_bf16(fabsf(e0-vm0.x), fabsf(e1-vm1.x));
        aw[3][q] = pk_bf16(fabsf(e0-vm0.y), fabsf(e1-vm1.y));
      }
      f32x4 acc = {0.f, 0.f, 0.f, 0.f};
      #pragma unroll
      for (int x = 0; x < 4; ++x){
        i32x4 av = {(int)aw[x][0], (int)aw[x][1], (int)aw[x][2], (int)aw[x][3]};
        i32x4 bv = *(const i32x4*)&s_bfrag[((x*2 + ot)*64 + l)*4];
        acc = __builtin_amdgcn_mfma_f32_16x16x32_bf16(
                __builtin_bit_cast(bf16x8s, av),
                __builtin_bit_cast(bf16x8s, bv), acc, 0, 0, 0);
      }
      // tanh + packed 5-shfl reduce over the 16 cols
      float v[4];
      #pragma unroll
      for (int r = 0; r < 4; ++r) v[r] = tanh_f(acc[r] + b1o) * w2o;
      const bool b3 = (l & 8) != 0;
      #pragma unroll
      for (int k = 0; k < 2; ++k){
        float send = b3 ? v[k] : v[k+2];
        float tt = __shfl_xor(send, 8);
        v[k] = (b3 ? v[k+2] : v[k]) + tt;
      }
      const bool b2_ = (l & 4) != 0;
      {
        float send = b2_ ? v[0] : v[1];
        float tt = __shfl_xor(send, 4);
        v[0] = (b2_ ? v[1] : v[0]) + tt;
      }
      v[0] += __shfl_xor(v[0], 2);
      v[0] += __shfl_xor(v[0], 1);
      if ((l & 3) == 0){
        int m_local = kg*4 + ((l >> 3) & 1)*2 + ((l >> 2) & 1);
        s_zpart[ot*32 + mt*16 + m_local] = v[0];
      }
    }
    __syncthreads();

    // ---- phase C: softmax on all lanes (combine ot-halves); weighted-t ----
    {
      float z  = s_zpart[o] + s_zpart[32 + o];
      float mx = z;
      #pragma unroll
      for (int s = 16; s > 0; s >>= 1) mx = fmaxf(mx, __shfl_xor(mx, s));
      float e  = __expf(z - mx);
      float sm = e;
      #pragma unroll
      for (int s = 16; s > 0; s >>= 1) sm += __shfl_xor(sm, s);
      float gval = e / sm;   // lane o holds gate for memory o
      float po = 0.f;
      #pragma unroll
      for (int ml = 0; ml < 4; ++ml)
        po += __shfl(gval, g*4 + ml) * tv[ml];
      s_opart[g*32 + o] = po;
    }
    __syncthreads();

    // ---- phase D: GRU gates, distributed, coalesced b128 weight loads ----
    {
      const int cc = (tid & 7) * 4;
      const int rr = tid >> 3;          // 0..31
      float4 o4 = make_float4(0,0,0,0);
      #pragma unroll
      for (int gg = 0; gg < 8; ++gg){
        float4 t = *(const float4*)&s_opart[gg*32 + cc];
        o4.x += t.x; o4.y += t.y; o4.z += t.z; o4.w += t.w;
      }
      float4 m4 = *(const float4*)&s_M[cc];
      #pragma unroll
      for (int k = 0; k < 3; ++k){
        int row = k*32 + rr;
        float4 wi = *(const float4*)(gru_w_ih + ((size_t)hop*96 + row)*32 + cc);
        float4 wh = *(const float4*)(gru_w_hh + ((size_t)hop*96 + row)*32 + cc);
        float ai = wi.x*o4.x + wi.y*o4.y + wi.z*o4.z + wi.w*o4.w;
        float ah = wh.x*m4.x + wh.y*m4.y + wh.z*m4.z + wh.w*m4.w;
        ai += __shfl_xor(ai,1); ai += __shfl_xor(ai,2); ai += __shfl_xor(ai,4);
        ah += __shfl_xor(ah,1); ah += __shfl_xor(ah,2); ah += __shfl_xor(ah,4);
        if ((tid & 7) == 0){
          s_gig[row]      = ai;
          s_gig[96 + row] = ah;
        }
      }
    }
    __syncthreads();

    // ---- phase E: GRU state update (lanes 0..31), biases from global ----
    if (tid < 32){
      const float* bih = gru_b_ih + hop*96;
      const float* bhh = gru_b_hh + hop*96;
      float ir = s_gig[o]       + bih[o];
      float iz = s_gig[32 + o]  + bih[32 + o];
      float in_= s_gig[64 + o]  + bih[64 + o];
      float hr = s_gig[96 + o]  + bhh[o];
      float hz = s_gig[128 + o] + bhh[32 + o];
      float hn = s_gig[160 + o] + bhh[64 + o];
      float r  = sigmoid_f(ir + hr);
      float zz = sigmoid_f(iz + hz);
      float n  = tanh_f(in_ + r*hn);
      float Mn = (1.f - zz)*n + zz*Mreg;
      Mreg = Mn;
      s_M[o] = Mn;
      s_vsM[o*2+1] = Mn;
    }
    __syncthreads();
  }

  // ---- epilogue: Mw = sigmoid(M @ ans_w.T + ans_b); out = vs . Mw ----
  {
    const int cc = (tid & 7) * 4;
    const int rr = tid >> 3;
    float4 m4 = *(const float4*)&s_M[cc];
    float4 aw = *(const float4*)(ans_w + (size_t)rr*32 + cc);
    float a = aw.x*m4.x + aw.y*m4.y + aw.z*m4.z + aw.w*m4.w;
    a += __shfl_xor(a,1); a += __shfl_xor(a,2); a += __shfl_xor(a,4);
    if ((tid & 7) == 0) s_zpart[rr] = sigmoid_f(a + ans_b[rr]);
  }
  __syncthreads();
  if (tid < 32){
    float val = s_vsM[o*2+0] * s_zpart[o];
    #pragma unroll
    for (int s = 16; s > 0; s >>= 1) val += __shfl_xor(val, s);
    if (tid == 0) out[b] = val;
  }
}

extern "C" void kernel_launch(void* const* d_in, const int* in_sizes, int n_in,
                              void* d_out, int out_size, void* d_ws, size_t ws_size,
                              hipStream_t stream) {
  const int*   h_i          = (const int*)  d_in[0];
  const int*   R_i          = (const int*)  d_in[1];
  const int*   t_i          = (const int*)  d_in[2];
  const int*   v_i          = (const int*)  d_in[3];
  const float* entity_emb   = (const float*)d_in[4];
  const float* relation_emb = (const float*)d_in[5];
  const float* agg_w1       = (const float*)d_in[6];
  const float* agg_b1       = (const float*)d_in[7];
  const float* agg_w2       = (const float*)d_in[8];
  const float* agg_b2       = (const float*)d_in[9];   // softmax-invariant, dropped
  const float* gru_w_ih     = (const float*)d_in[10];
  const float* gru_w_hh     = (const float*)d_in[11];
  const float* gru_b_ih     = (const float*)d_in[12];
  const float* gru_b_hh     = (const float*)d_in[13];
  const float* ans_w        = (const float*)d_in[14];
  const float* ans_b        = (const float*)d_in[15];
  (void)agg_b2;
  float* outp = (float*)d_out;

  const int batch = in_sizes[3];
  ripple_fused<<<batch, 256, 0, stream>>>(
      h_i, R_i, t_i, v_i, entity_emb, relation_emb,
      agg_w1, agg_b1, agg_w2, agg_b2,
      gru_w_ih, gru_w_hh, gru_b_ih, gru_b_hh,
      ans_w, ans_b, outp);
}

// Round 11
// 42.208 us; speedup vs baseline: 1.4597x; 1.0727x over previous
//
#include <hip/hip_runtime.h>
#include <hip/hip_bf16.h>

// RippleNetPlus fused — 1 block (256 thr) per TWO batch elements.
// DIM=32, HOP=2, MEM=32, BATCH=2048 -> grid 1024, 4 blocks/CU (LDS 29.2KB).
//
// Round 11: 2 elements/block. Rationale (R10 PMC: VALU 36%, HBM 4%, Mfma 1%,
// 64% idle = correlated lockstep stalls + tail):
//  - per-element barrier count halves (11 per 2 elements);
//  - every phase gains an independent 2nd instruction stream (element B):
//    dual-chain phase-A gather doubles memory-level parallelism;
//  - 1024 blocks x 4 waves = 16 waves/CU demand -> VGPR<=128 is free
//    (the 64-VGPR cliff no longer binds; dual chains affordable);
//  - phase D loads GRU weights once for both elements.
// Phase bodies = R10 (verified absmax 0): same MFMA tiles, same layouts.

#define NHOP 2

typedef __attribute__((ext_vector_type(4)))  float f32x4;
typedef __attribute__((ext_vector_type(8)))  short bf16x8s;
typedef __attribute__((ext_vector_type(4)))  int   i32x4;

__device__ __forceinline__ float sigmoid_f(float x){ return 1.0f/(1.0f+__expf(-x)); }
__device__ __forceinline__ float tanh_f(float x){
  float e = __expf(2.0f*x);
  return 1.0f - 2.0f/(e + 1.0f);
}
__device__ __forceinline__ unsigned pk_bf16(float lo, float hi){
  __hip_bfloat162 h = __float22bfloat162_rn(make_float2(lo, hi));
  return *reinterpret_cast<unsigned*>(&h);
}
__device__ __forceinline__ float bfly8(float p[8], bool bb4, bool bb2, bool bb1){
  #pragma unroll
  for (int k = 0; k < 4; ++k){
    float send = bb4 ? p[k] : p[k+4];
    float t = __shfl_xor(send, 4);
    p[k] = (bb4 ? p[k+4] : p[k]) + t;
  }
  #pragma unroll
  for (int k = 0; k < 2; ++k){
    float send = bb2 ? p[k] : p[k+2];
    float t = __shfl_xor(send, 2);
    p[k] = (bb2 ? p[k+2] : p[k]) + t;
  }
  float send = bb1 ? p[0] : p[1];
  float t = __shfl_xor(send, 1);
  return (bb1 ? p[1] : p[0]) + t;
}

__global__ __launch_bounds__(256) void ripple_fused(
    const int* __restrict__ h_i, const int* __restrict__ R_i, const int* __restrict__ t_i,
    const int* __restrict__ v_i,
    const float* __restrict__ entity_emb, const float* __restrict__ relation_emb,
    const float* __restrict__ agg_w1, const float* __restrict__ agg_b1,
    const float* __restrict__ agg_w2, const float* __restrict__ agg_b2,
    const float* __restrict__ gru_w_ih, const float* __restrict__ gru_w_hh,
    const float* __restrict__ gru_b_ih, const float* __restrict__ gru_b_hh,
    const float* __restrict__ ans_w, const float* __restrict__ ans_b,
    float* __restrict__ out, int batch)
{
  __shared__ __align__(16) int   s_bfrag[8*64*4];     // 8 KB   shared B-frags
  __shared__ __align__(16) float s_rhA[2][2][32*33];  // 16.5KB [elem][hop] stride-33
  __shared__ __align__(16) float s_vsM[2][64];        // [elem][i*2+{vs,M}]
  __shared__ __align__(16) float s_zpart[2][64];      // [elem][ot*32+m]
  __shared__ __align__(16) float s_opart[2][4*32];    // [elem][w][o]
  __shared__ __align__(16) float s_M[2][32];
  __shared__ __align__(16) float s_gig[2][192];       // [elem] gi[0:96] gh[96:192]

  const int bid = blockIdx.x;
  const int eA  = bid*2;
  const int eB  = (eA + 1 < batch) ? eA + 1 : eA;
  const int tid = threadIdx.x;
  const int g   = tid >> 5;   // group 0..7
  const int o   = tid & 31;
  const int l   = tid & 63;   // lane
  const int w   = tid >> 6;   // wave 0..3
  const int c   = o & 7;
  const int r_  = o >> 3;
  const bool bb4 = (c & 4) != 0;
  const bool bb2 = (c & 2) != 0;
  const bool bb1 = (c & 1) != 0;

  // ---- init: stage B-fragments (16x16x32 layout; same as R10) ----
  #pragma unroll
  for (int k = 0; k < 2; ++k){
    int s  = tid + k*256;           // 0..511
    int f  = s >> 6, li = s & 63;
    int x  = f >> 1, otf = f & 1;
    const float* src = agg_w1 + (otf*16 + (li & 15))*128 + x*32 + ((li >> 4) & 3)*8;
    float4 f0 = *(const float4*)src;
    float4 f1 = *(const float4*)(src + 4);
    *(int4*)&s_bfrag[s*4] = make_int4((int)pk_bf16(f0.x, f0.y), (int)pk_bf16(f0.z, f0.w),
                                      (int)pk_bf16(f1.x, f1.y), (int)pk_bf16(f1.z, f1.w));
  }
  if (tid < 64){
    int e  = tid >> 5, oo = tid & 31;
    float v = entity_emb[(size_t)v_i[e ? eB : eA]*32 + oo];
    s_vsM[e][oo*2+0] = v; s_vsM[e][oo*2+1] = v; s_M[e][oo] = v;
  }

  // ---- phase A (both hops x both elems): dual-chain Rh gather ----
  {
    const int iA = c*4 + r_;
    #pragma unroll 1
    for (int it = 0; it < 8; ++it){
      const int hp = it >> 2;
      const int ml = it & 3;
      const int m  = g*4 + ml;
      int rAi = R_i[(eA*NHOP + hp)*32 + m];
      int hAi = h_i[(eA*NHOP + hp)*32 + m];
      int rBi = R_i[(eB*NHOP + hp)*32 + m];
      int hBi = h_i[(eB*NHOP + hp)*32 + m];
      const float* RbA = relation_emb + (size_t)rAi*1024;
      const float* RbB = relation_emb + (size_t)rBi*1024;
      float4 hvA = *(const float4*)(entity_emb + (size_t)hAi*32 + c*4);
      float4 hvB = *(const float4*)(entity_emb + (size_t)hBi*32 + c*4);
      float pA[8], pB[8];
      #pragma unroll
      for (int q = 0; q < 8; ++q){
        float4 rv = *(const float4*)(RbA + q*128 + o*4);
        pA[q] = rv.x*hvA.x + rv.y*hvA.y + rv.z*hvA.z + rv.w*hvA.w;
      }
      #pragma unroll
      for (int q = 0; q < 8; ++q){
        float4 rv = *(const float4*)(RbB + q*128 + o*4);
        pB[q] = rv.x*hvB.x + rv.y*hvB.y + rv.z*hvB.z + rv.w*hvB.w;
      }
      float a0 = bfly8(pA, bb4, bb2, bb1);
      float a1 = bfly8(pB, bb4, bb2, bb1);
      s_rhA[0][hp][m*33 + iA] = a0;
      s_rhA[1][hp][m*33 + iA] = a1;
    }
  }
  __syncthreads();

  // per-wave tile coords (phase B) — same mapping as R10
  const int mt  = w >> 1, ot = w & 1;
  const int col = l & 15;
  const int kg  = l >> 4;
  const float b1o = agg_b1[ot*16 + col];
  const float w2o = agg_w2[ot*16 + col];

  for (int hop = 0; hop < NHOP; ++hop){
    // ---- t-row prefetch for both elements ----
    float tvA[4], tvB[4];
    #pragma unroll
    for (int ml = 0; ml < 4; ++ml){
      tvA[ml] = entity_emb[(size_t)t_i[(eA*NHOP + hop)*32 + g*4 + ml]*32 + o];
      tvB[ml] = entity_emb[(size_t)t_i[(eB*NHOP + hop)*32 + g*4 + ml]*32 + o];
    }

    // ---- phase B: wave tile via mfma_16x16x32, both elements ----
    {
      i32x4 bv[4];
      #pragma unroll
      for (int x = 0; x < 4; ++x)
        bv[x] = *(const i32x4*)&s_bfrag[((x*2 + ot)*64 + l)*4];
      #pragma unroll
      for (int e = 0; e < 2; ++e){
        const float* rp = &s_rhA[e][hop][(mt*16 + col)*33 + kg*8];
        float4 q0 = *(const float4*)(rp);
        float4 q1 = *(const float4*)(rp + 4);
        float rh[8] = {q0.x,q0.y,q0.z,q0.w,q1.x,q1.y,q1.z,q1.w};
        unsigned aw[4][4];
        #pragma unroll
        for (int q = 0; q < 4; ++q){
          int i0 = kg*8 + 2*q;
          float2 vm0 = *(const float2*)&s_vsM[e][i0*2];
          float2 vm1 = *(const float2*)&s_vsM[e][(i0+1)*2];
          float e0 = rh[2*q], e1 = rh[2*q+1];
          aw[0][q] = pk_bf16(e0*vm0.x,        e1*vm1.x);
          aw[1][q] = pk_bf16(e0*vm0.y,        e1*vm1.y);
          aw[2][q] = pk_bf16(fabsf(e0-vm0.x), fabsf(e1-vm1.x));
          aw[3][q] = pk_bf16(fabsf(e0-vm0.y), fabsf(e1-vm1.y));
        }
        f32x4 acc = {0.f, 0.f, 0.f, 0.f};
        #pragma unroll
        for (int x = 0; x < 4; ++x){
          i32x4 av = {(int)aw[x][0], (int)aw[x][1], (int)aw[x][2], (int)aw[x][3]};
          acc = __builtin_amdgcn_mfma_f32_16x16x32_bf16(
                  __builtin_bit_cast(bf16x8s, av),
                  __builtin_bit_cast(bf16x8s, bv[x]), acc, 0, 0, 0);
        }
        float v[4];
        #pragma unroll
        for (int r = 0; r < 4; ++r) v[r] = tanh_f(acc[r] + b1o) * w2o;
        const bool b3 = (l & 8) != 0;
        #pragma unroll
        for (int k = 0; k < 2; ++k){
          float send = b3 ? v[k] : v[k+2];
          float tt = __shfl_xor(send, 8);
          v[k] = (b3 ? v[k+2] : v[k]) + tt;
        }
        const bool b2_ = (l & 4) != 0;
        {
          float send = b2_ ? v[0] : v[1];
          float tt = __shfl_xor(send, 4);
          v[0] = (b2_ ? v[1] : v[0]) + tt;
        }
        v[0] += __shfl_xor(v[0], 2);
        v[0] += __shfl_xor(v[0], 1);
        if ((l & 3) == 0){
          int m_local = kg*4 + ((l >> 3) & 1)*2 + ((l >> 2) & 1);
          s_zpart[e][ot*32 + mt*16 + m_local] = v[0];
        }
      }
    }
    __syncthreads();

    // ---- phase C: softmax (all lanes) + weighted-t, both elements;
    //      in-wave cross-group combine via shfl_xor(32) -> 4 partials ----
    #pragma unroll
    for (int e = 0; e < 2; ++e){
      float z  = s_zpart[e][o] + s_zpart[e][32 + o];
      float mx = z;
      #pragma unroll
      for (int s = 16; s > 0; s >>= 1) mx = fmaxf(mx, __shfl_xor(mx, s));
      float ex = __expf(z - mx);
      float sm = ex;
      #pragma unroll
      for (int s = 16; s > 0; s >>= 1) sm += __shfl_xor(sm, s);
      float gval = ex / sm;
      float po = 0.f;
      #pragma unroll
      for (int ml = 0; ml < 4; ++ml)
        po += __shfl(gval, g*4 + ml) * (e == 0 ? tvA[ml] : tvB[ml]);
      po += __shfl_xor(po, 32);
      if (l < 32) s_opart[e][w*32 + o] = po;
    }
    __syncthreads();

    // ---- phase D: GRU gates, weights loaded once for both elements ----
    {
      const int cc = (tid & 7) * 4;
      const int rr = tid >> 3;
      float4 oA = make_float4(0,0,0,0), oB = make_float4(0,0,0,0);
      #pragma unroll
      for (int gg = 0; gg < 4; ++gg){
        float4 ta = *(const float4*)&s_opart[0][gg*32 + cc];
        float4 tb = *(const float4*)&s_opart[1][gg*32 + cc];
        oA.x += ta.x; oA.y += ta.y; oA.z += ta.z; oA.w += ta.w;
        oB.x += tb.x; oB.y += tb.y; oB.z += tb.z; oB.w += tb.w;
      }
      float4 mA = *(const float4*)&s_M[0][cc];
      float4 mB = *(const float4*)&s_M[1][cc];
      #pragma unroll
      for (int k = 0; k < 3; ++k){
        int row = k*32 + rr;
        float4 wi = *(const float4*)(gru_w_ih + ((size_t)hop*96 + row)*32 + cc);
        float4 wh = *(const float4*)(gru_w_hh + ((size_t)hop*96 + row)*32 + cc);
        float aiA = wi.x*oA.x + wi.y*oA.y + wi.z*oA.z + wi.w*oA.w;
        float ahA = wh.x*mA.x + wh.y*mA.y + wh.z*mA.z + wh.w*mA.w;
        float aiB = wi.x*oB.x + wi.y*oB.y + wi.z*oB.z + wi.w*oB.w;
        float ahB = wh.x*mB.x + wh.y*mB.y + wh.z*mB.z + wh.w*mB.w;
        aiA += __shfl_xor(aiA,1); aiA += __shfl_xor(aiA,2); aiA += __shfl_xor(aiA,4);
        ahA += __shfl_xor(ahA,1); ahA += __shfl_xor(ahA,2); ahA += __shfl_xor(ahA,4);
        aiB += __shfl_xor(aiB,1); aiB += __shfl_xor(aiB,2); aiB += __shfl_xor(aiB,4);
        ahB += __shfl_xor(ahB,1); ahB += __shfl_xor(ahB,2); ahB += __shfl_xor(ahB,4);
        if ((tid & 7) == 0){
          s_gig[0][row]      = aiA;
          s_gig[0][96 + row] = ahA;
          s_gig[1][row]      = aiB;
          s_gig[1][96 + row] = ahB;
        }
      }
    }
    __syncthreads();

    // ---- phase E: GRU update — wave 0, lanes 0-31 elem A, 32-63 elem B ----
    if (tid < 64){
      int e = tid >> 5, oo = tid & 31;
      const float* bih = gru_b_ih + hop*96;
      const float* bhh = gru_b_hh + hop*96;
      float ir = s_gig[e][oo]       + bih[oo];
      float iz = s_gig[e][32 + oo]  + bih[32 + oo];
      float in_= s_gig[e][64 + oo]  + bih[64 + oo];
      float hr = s_gig[e][96 + oo]  + bhh[oo];
      float hz = s_gig[e][128 + oo] + bhh[32 + oo];
      float hn = s_gig[e][160 + oo] + bhh[64 + oo];
      float r  = sigmoid_f(ir + hr);
      float zz = sigmoid_f(iz + hz);
      float n  = tanh_f(in_ + r*hn);
      float Mn = (1.f - zz)*n + zz*s_M[e][oo];
      s_M[e][oo] = Mn;
      s_vsM[e][oo*2+1] = Mn;
    }
    __syncthreads();
  }

  // ---- epilogue: Mw = sigmoid(M @ ans_w.T + ans_b); out = vs . Mw ----
  #pragma unroll
  for (int e = 0; e < 2; ++e){
    const int cc = (tid & 7) * 4;
    const int rr = tid >> 3;
    float4 m4 = *(const float4*)&s_M[e][cc];
    float4 aw = *(const float4*)(ans_w + (size_t)rr*32 + cc);
    float a = aw.x*m4.x + aw.y*m4.y + aw.z*m4.z + aw.w*m4.w;
    a += __shfl_xor(a,1); a += __shfl_xor(a,2); a += __shfl_xor(a,4);
    if ((tid & 7) == 0) s_zpart[e][rr] = sigmoid_f(a + ans_b[rr]);
  }
  __syncthreads();
  if (tid < 64){
    int e = tid >> 5, oo = tid & 31;
    float val = s_vsM[e][oo*2+0] * s_zpart[e][oo];
    #pragma unroll
    for (int s = 16; s > 0; s >>= 1) val += __shfl_xor(val, s);
    if (oo == 0) out[e ? eB : eA] = val;
  }
}

extern "C" void kernel_launch(void* const* d_in, const int* in_sizes, int n_in,
                              void* d_out, int out_size, void* d_ws, size_t ws_size,
                              hipStream_t stream) {
  const int*   h_i          = (const int*)  d_in[0];
  const int*   R_i          = (const int*)  d_in[1];
  const int*   t_i          = (const int*)  d_in[2];
  const int*   v_i          = (const int*)  d_in[3];
  const float* entity_emb   = (const float*)d_in[4];
  const float* relation_emb = (const float*)d_in[5];
  const float* agg_w1       = (const float*)d_in[6];
  const float* agg_b1       = (const float*)d_in[7];
  const float* agg_w2       = (const float*)d_in[8];
  const float* agg_b2       = (const float*)d_in[9];   // softmax-invariant, dropped
  const float* gru_w_ih     = (const float*)d_in[10];
  const float* gru_w_hh     = (const float*)d_in[11];
  const float* gru_b_ih     = (const float*)d_in[12];
  const float* gru_b_hh     = (const float*)d_in[13];
  const float* ans_w        = (const float*)d_in[14];
  const float* ans_b        = (const float*)d_in[15];
  (void)agg_b2;
  float* outp = (float*)d_out;

  const int batch = in_sizes[3];
  const int grid  = (batch + 1) / 2;
  ripple_fused<<<grid, 256, 0, stream>>>(
      h_i, R_i, t_i, v_i, entity_emb, relation_emb,
      agg_w1, agg_b1, agg_w2, agg_b2,
      gru_w_ih, gru_w_hh, gru_b_ih, gru_b_hh,
      ans_w, ans_b, outp, batch);
}